// Round 1
// 3011.566 us; speedup vs baseline: 1.2173x; 1.2173x over previous
//
#include <hip/hip_runtime.h>
#include <hip/hip_cooperative_groups.h>

namespace cg = cooperative_groups;

#define BB 64
#define LL 32
#define DD 512
#define HH 1024
#define GG 4096   // 4*H
#define VV 32000
#define EHH 512
#define ELL 40

// ws layout (float units)
#define OFF_H   0                          // hstates: [33][64][1024] (row 0 = h0)
#define OFF_HT  (33*BB*HH)                 // hT: [2][256][64][4]  (h transposed, parity dbuf)
#define OFF_RM  (OFF_HT + 2*256*BB*4)      // rowmax: 2048 u32 keys
#define OFF_GX  (OFF_RM + 2048)            // gates_x: [32][64][4096]; later aliased by Apack

typedef __attribute__((ext_vector_type(8))) short bf16x8;
typedef __attribute__((ext_vector_type(4))) float f32x4;

__device__ __forceinline__ unsigned long long packkey(float v, int n) {
    unsigned u = __float_as_uint(v);
    u = (u & 0x80000000u) ? ~u : (u | 0x80000000u);
    return ((unsigned long long)u << 32) | (unsigned)(0x7FFFFFFF - n);
}
__device__ __forceinline__ unsigned key32(float v) {
    unsigned u = __float_as_uint(v);
    return (u & 0x80000000u) ? ~u : (u | 0x80000000u);
}
__device__ __forceinline__ float keyinv(unsigned k) {
    unsigned u = (k & 0x80000000u) ? (k & 0x7FFFFFFFu) : ~k;
    return __uint_as_float(u);
}
// f32 -> bf16 (RNE), pure bit ops (no header-version dependence)
__device__ __forceinline__ unsigned short f2bf(float v) {
    unsigned u = __float_as_uint(v);
    return (unsigned short)((u + 0x7FFFu + ((u >> 16) & 1u)) >> 16);
}
__device__ __forceinline__ float bf2f(unsigned short b) {
    return __uint_as_float(((unsigned)b) << 16);
}

// ---- hx0 = hidden_state[:, -1, :] @ W_p.T + b_p ; also seed hT[0]; zero rowmax ----
__global__ __launch_bounds__(128) void init_kernel(
    const float* __restrict__ hid, const float* __restrict__ Wp,
    const float* __restrict__ bp, float* __restrict__ hst,
    float* __restrict__ hT, unsigned* __restrict__ rowmax)
{
    int b = blockIdx.x;
    int h = blockIdx.y * 128 + threadIdx.x;
    const float4* hrow = (const float4*)(hid + ((size_t)b*ELL + (ELL-1))*EHH);
    const float4* wrow = (const float4*)(Wp + (size_t)h*EHH);
    float acc = 0.f;
    #pragma unroll 4
    for (int k = 0; k < EHH/4; ++k) {
        float4 a = hrow[k], w = wrow[k];
        acc += a.x*w.x + a.y*w.y + a.z*w.z + a.w*w.w;
    }
    float v = acc + bp[h];
    hst[(size_t)b*HH + h] = v;
    hT[((h>>2)*64 + b)*4 + (h&3)] = v;      // parity-0 buffer
    int tg = (b*8 + blockIdx.y)*128 + threadIdx.x;
    if (tg < LL*BB) rowmax[tg] = 0u;
}

// ---- gates_x[l*64+b][g] = sent[b][l][:] . W_ih[g][:] + b_ih[g] + b_hh[g] (unchanged) ----
#define KT 16
__global__ __launch_bounds__(256) void gates_x_kernel(
    const float* __restrict__ x, const float* __restrict__ Wih,
    const float* __restrict__ bih, const float* __restrict__ bhh,
    float* __restrict__ gx)
{
    __shared__ float As[KT][68];
    __shared__ float Bs[KT][68];
    const int l  = blockIdx.x;
    const int n0 = blockIdx.y * 64;
    const int tid = threadIdx.x;
    const int tx = tid & 15, ty = tid >> 4;
    float acc[4][4] = {};
    for (int k0 = 0; k0 < DD; k0 += KT) {
        int i = tid * 4;
        int m = i >> 4, kk = i & 15;
        float4 a = *(const float4*)(x + ((size_t)m*LL + l)*DD + k0 + kk);
        As[kk+0][m]=a.x; As[kk+1][m]=a.y; As[kk+2][m]=a.z; As[kk+3][m]=a.w;
        float4 w = *(const float4*)(Wih + (size_t)(n0+m)*DD + k0 + kk);
        Bs[kk+0][m]=w.x; Bs[kk+1][m]=w.y; Bs[kk+2][m]=w.z; Bs[kk+3][m]=w.w;
        __syncthreads();
        #pragma unroll
        for (int k = 0; k < KT; ++k) {
            float4 av = *(const float4*)&As[k][ty*4];
            float4 bv = *(const float4*)&Bs[k][tx*4];
            float aa[4] = {av.x,av.y,av.z,av.w};
            float bb2[4] = {bv.x,bv.y,bv.z,bv.w};
            #pragma unroll
            for (int i2 = 0; i2 < 4; ++i2)
                #pragma unroll
                for (int j = 0; j < 4; ++j)
                    acc[i2][j] += aa[i2]*bb2[j];
        }
        __syncthreads();
    }
    #pragma unroll
    for (int i2 = 0; i2 < 4; ++i2) {
        int m = ty*4 + i2;
        int r = l*64 + m;
        int n = n0 + tx*4;
        float4 o;
        o.x = acc[i2][0] + bih[n+0] + bhh[n+0];
        o.y = acc[i2][1] + bih[n+1] + bhh[n+1];
        o.z = acc[i2][2] + bih[n+2] + bhh[n+2];
        o.w = acc[i2][3] + bih[n+3] + bhh[n+3];
        *(float4*)(gx + (size_t)r*GG + n) = o;
    }
}

// ---- persistent LSTM: 256 wgs (1/CU), W_hh slice in LDS once, 32 steps w/ grid sync ----
// wg w owns h-indices h0=4w..4w+3 (16 Whh rows). Compute: wave=gate g, lane=batch b,
// acc[j] over j=0..3. Update: wave=j, lane=b, c-state in a register for all 32 steps.
__global__ __launch_bounds__(256) void lstm_persist_kernel(
    const float* __restrict__ gx,    // [32][64][4096] pre-biased
    const float* __restrict__ Whh,   // [4096][1024]
    float* __restrict__ hst,         // [33][64][1024]
    float* __restrict__ hT)          // [2][256][64][4]
{
    extern __shared__ float smem[];
    float* Ws = smem;                // [16][1024] = 64 KB
    float* Gs = smem + 16*1024;      // [16][64]   =  4 KB
    const int w = blockIdx.x;
    const int h0 = w*4;
    const int tid = threadIdx.x;
    const int wave = tid >> 6;       // gate in compute phase / j in update phase
    const int lane = tid & 63;       // batch

    #pragma unroll
    for (int r16 = 0; r16 < 16; ++r16) {
        int g = r16 >> 2, j = r16 & 3;
        *(float4*)&Ws[r16*1024 + tid*4] =
            *(const float4*)(Whh + ((size_t)(g*HH + h0 + j))*HH + tid*4);
    }
    float c = 0.f;
    cg::grid_group grid = cg::this_grid();
    __syncthreads();

    const float* wr0 = &Ws[(wave*4+0)*1024];
    const float* wr1 = &Ws[(wave*4+1)*1024];
    const float* wr2 = &Ws[(wave*4+2)*1024];
    const float* wr3 = &Ws[(wave*4+3)*1024];

    for (int s = 1; s <= LL; ++s) {
        const float* hp  = hT + (((s-1)&1) ? 65536 : 0) + lane*4;
        const float* gxs = gx + ((size_t)(s-1))*BB*GG + (size_t)lane*GG + wave*HH + h0;
        float add0 = gxs[0], add1 = gxs[1], add2 = gxs[2], add3 = gxs[3];
        float a0=0.f, a1=0.f, a2=0.f, a3=0.f;
        #pragma unroll 4
        for (int kq = 0; kq < 256; ++kq) {
            float4 hv = *(const float4*)(hp + (size_t)kq*256);
            float4 w0 = *(const float4*)(wr0 + kq*4);
            float4 w1 = *(const float4*)(wr1 + kq*4);
            float4 w2 = *(const float4*)(wr2 + kq*4);
            float4 w3 = *(const float4*)(wr3 + kq*4);
            a0 += hv.x*w0.x + hv.y*w0.y + hv.z*w0.z + hv.w*w0.w;
            a1 += hv.x*w1.x + hv.y*w1.y + hv.z*w1.z + hv.w*w1.w;
            a2 += hv.x*w2.x + hv.y*w2.y + hv.z*w2.z + hv.w*w2.w;
            a3 += hv.x*w3.x + hv.y*w3.y + hv.z*w3.z + hv.w*w3.w;
        }
        Gs[(wave*4+0)*64 + lane] = a0 + add0;
        Gs[(wave*4+1)*64 + lane] = a1 + add1;
        Gs[(wave*4+2)*64 + lane] = a2 + add2;
        Gs[(wave*4+3)*64 + lane] = a3 + add3;
        __syncthreads();
        // update phase: this thread owns h = h0 + wave for batch=lane
        float gi = Gs[( 0 + wave)*64 + lane];
        float gf = Gs[( 4 + wave)*64 + lane];
        float gg = Gs[( 8 + wave)*64 + lane];
        float go = Gs[(12 + wave)*64 + lane];
        float si = 1.f/(1.f + expf(-gi));
        float sf = 1.f/(1.f + expf(-gf));
        float so = 1.f/(1.f + expf(-go));
        float cn = sf*c + si*tanhf(gg);
        float hn = so*tanhf(cn);
        c = cn;
        int h = h0 + wave;
        hst[((size_t)s*BB + lane)*HH + h] = hn;
        float* hTn = hT + ((s&1) ? 65536 : 0);
        hTn[((h>>2)*64 + lane)*4 + (h&3)] = hn;
        grid.sync();
    }
}

// ---- split hs rows (2048x1024 f32) into MFMA-fragment-linear bf16 hi/lo ----
// Apack[m16][kstep][lane][8]: lane l -> row m16*16+(l&15), k = kstep*32+(l>>4)*8+j
__global__ __launch_bounds__(256) void hsplit_kernel(
    const float* __restrict__ hs, unsigned short* __restrict__ Ahi,
    unsigned short* __restrict__ Alo)
{
    int t = blockIdx.x*256 + threadIdx.x;       // 2048 rows x 128 k-octets
    int row = t >> 7, ko = (t & 127) << 3;
    const float* src = hs + (size_t)row*HH + ko;
    float4 f0 = *(const float4*)(src);
    float4 f1 = *(const float4*)(src + 4);
    float vs[8] = {f0.x,f0.y,f0.z,f0.w,f1.x,f1.y,f1.z,f1.w};
    union { bf16x8 v; unsigned short u[8]; } hi, lo;
    #pragma unroll
    for (int e = 0; e < 8; ++e) {
        unsigned short h = f2bf(vs[e]);
        hi.u[e] = h;
        lo.u[e] = f2bf(vs[e] - bf2f(h));
    }
    size_t off = ((((size_t)(row>>4)*32 + (ko>>5))*64) + ((ko&31)>>3)*16 + (row&15))*8;
    *(bf16x8*)(Ahi + off) = hi.v;
    *(bf16x8*)(Alo + off) = lo.v;
}

// ---- logits = hs @ W_v.T + b_v via bf16x3 split MFMA; approx per-row max tracked ----
__global__ __launch_bounds__(256, 2) void logits_mfma_kernel(
    const unsigned short* __restrict__ Ahi, const unsigned short* __restrict__ Alo,
    const float* __restrict__ Wv, const float* __restrict__ bv,
    float* __restrict__ out, unsigned* __restrict__ rowmax)
{
    // Bs[kslot][col] : 8 bf16 (k-major) -> conflict-free ds_write and B-frag ds_read
    __shared__ bf16x8 Bhi[4][128];
    __shared__ bf16x8 Blo[4][128];
    const int rb = blockIdx.x;        // row block 0..15   (128 rows)
    const int cb = blockIdx.y;        // col block 0..249  (128 cols)
    const int n0 = cb*128;
    const int tid = threadIdx.x;
    const int wid = tid >> 6, lane = tid & 63;
    const int wy = wid >> 1, wx = wid & 1;      // 2x2 waves, 64x64 each
    const int l15 = lane & 15, l4 = lane >> 4;
    f32x4 acc[4][4] = {};

    const int sc = tid >> 1, skh = tid & 1;     // staging: col 0..127, k-half 0..1
    const float* wsrc = Wv + (size_t)(n0 + sc)*HH + skh*16;
    const size_t abase = (size_t)(rb*8 + wy*4)*32;

    for (int ks = 0; ks < 32; ++ks) {
        float4 f0 = *(const float4*)(wsrc + ks*32);
        float4 f1 = *(const float4*)(wsrc + ks*32 + 4);
        float4 f2 = *(const float4*)(wsrc + ks*32 + 8);
        float4 f3 = *(const float4*)(wsrc + ks*32 + 12);
        __syncthreads();
        {
            float va[8] = {f0.x,f0.y,f0.z,f0.w,f1.x,f1.y,f1.z,f1.w};
            float vb[8] = {f2.x,f2.y,f2.z,f2.w,f3.x,f3.y,f3.z,f3.w};
            union { bf16x8 v; unsigned short u[8]; } h0, l0, h1, l1;
            #pragma unroll
            for (int e = 0; e < 8; ++e) {
                unsigned short ha = f2bf(va[e]);
                h0.u[e] = ha; l0.u[e] = f2bf(va[e] - bf2f(ha));
                unsigned short hb = f2bf(vb[e]);
                h1.u[e] = hb; l1.u[e] = f2bf(vb[e] - bf2f(hb));
            }
            Bhi[skh*2+0][sc] = h0.v;  Blo[skh*2+0][sc] = l0.v;
            Bhi[skh*2+1][sc] = h1.v;  Blo[skh*2+1][sc] = l1.v;
        }
        __syncthreads();
        bf16x8 ah[4], al[4], bh[4], bl[4];
        #pragma unroll
        for (int mf = 0; mf < 4; ++mf) {
            size_t o = ((abase + (size_t)mf*32 + ks)*64 + lane)*8;
            ah[mf] = *(const bf16x8*)(Ahi + o);
            al[mf] = *(const bf16x8*)(Alo + o);
        }
        #pragma unroll
        for (int nf = 0; nf < 4; ++nf) {
            int cc = wx*64 + nf*16 + l15;
            bh[nf] = Bhi[l4][cc];
            bl[nf] = Blo[l4][cc];
        }
        #pragma unroll
        for (int mf = 0; mf < 4; ++mf)
            #pragma unroll
            for (int nf = 0; nf < 4; ++nf) {
                acc[mf][nf] = __builtin_amdgcn_mfma_f32_16x16x32_bf16(ah[mf], bh[nf], acc[mf][nf], 0,0,0);
                acc[mf][nf] = __builtin_amdgcn_mfma_f32_16x16x32_bf16(ah[mf], bl[nf], acc[mf][nf], 0,0,0);
                acc[mf][nf] = __builtin_amdgcn_mfma_f32_16x16x32_bf16(al[mf], bh[nf], acc[mf][nf], 0,0,0);
            }
    }
    // epilogue: C/D layout col = lane&15, row = (lane>>4)*4 + j  [m89-verified]
    unsigned rk[4][4];
    #pragma unroll
    for (int mf = 0; mf < 4; ++mf)
        #pragma unroll
        for (int j = 0; j < 4; ++j) rk[mf][j] = 0u;
    #pragma unroll
    for (int mf = 0; mf < 4; ++mf) {
        int rowg = rb*128 + wy*64 + mf*16 + l4*4;
        #pragma unroll
        for (int nf = 0; nf < 4; ++nf) {
            int col = n0 + wx*64 + nf*16 + l15;
            float bvv = bv[col];
            #pragma unroll
            for (int j = 0; j < 4; ++j) {
                float v = acc[mf][nf][j] + bvv;
                int row = rowg + j;
                int b = row & 63, l = row >> 6;
                out[((size_t)b*LL + l)*VV + col] = v;
                unsigned key = key32(v);
                if (key > rk[mf][j]) rk[mf][j] = key;
            }
        }
    }
    #pragma unroll
    for (int o = 1; o < 16; o <<= 1)
        #pragma unroll
        for (int mf = 0; mf < 4; ++mf)
            #pragma unroll
            for (int j = 0; j < 4; ++j) {
                unsigned t = __shfl_xor(rk[mf][j], o);
                if (t > rk[mf][j]) rk[mf][j] = t;
            }
    if (l15 == 0) {
        #pragma unroll
        for (int mf = 0; mf < 4; ++mf)
            #pragma unroll
            for (int j = 0; j < 4; ++j)
                atomicMax(&rowmax[rb*128 + wy*64 + mf*16 + l4*4 + j], rk[mf][j]);
    }
}

// ---- exact-rescued argmax: candidates within tau of approx max get exact fp32 dots ----
__global__ __launch_bounds__(256) void argmax_kernel(
    const float* __restrict__ out, const unsigned* __restrict__ rowmax,
    const float* __restrict__ hs, const float* __restrict__ Wv,
    const float* __restrict__ bv, float* __restrict__ pred)
{
    const int r = blockIdx.x;            // r = l*64 + b
    const int b = r & 63, l = r >> 6;
    const int tid = threadIdx.x;
    const float* row = out + ((size_t)b*LL + l)*VV;
    const float thr = keyinv(rowmax[r]) - 2e-3f;   // tau >= 2*worst-case bf16x3 error
    __shared__ int cnt;
    __shared__ int cand[32];
    __shared__ float ps[4];
    if (tid == 0) cnt = 0;
    __syncthreads();
    for (int i = tid*4; i < VV; i += 1024) {
        float4 v = *(const float4*)(row + i);
        if (v.x >= thr) { int p = atomicAdd(&cnt,1); if (p < 32) cand[p] = i; }
        if (v.y >= thr) { int p = atomicAdd(&cnt,1); if (p < 32) cand[p] = i+1; }
        if (v.z >= thr) { int p = atomicAdd(&cnt,1); if (p < 32) cand[p] = i+2; }
        if (v.w >= thr) { int p = atomicAdd(&cnt,1); if (p < 32) cand[p] = i+3; }
    }
    __syncthreads();
    int nc = cnt < 32 ? cnt : 32;
    unsigned long long best = 0ULL;
    const float* hrow = hs + (size_t)r*HH;
    float4 a = *(const float4*)(hrow + tid*4);
    for (int ci = 0; ci < nc; ++ci) {
        int n = cand[ci];
        float4 wv = *(const float4*)(Wv + (size_t)n*HH + tid*4);
        float p = a.x*wv.x + a.y*wv.y + a.z*wv.z + a.w*wv.w;
        #pragma unroll
        for (int o = 1; o < 64; o <<= 1) p += __shfl_xor(p, o);
        if ((tid & 63) == 0) ps[tid >> 6] = p;
        __syncthreads();
        if (tid == 0) {
            float tot = ps[0] + ps[1] + ps[2] + ps[3] + bv[n];
            unsigned long long k2 = packkey(tot, n);
            if (k2 > best) best = k2;
        }
        __syncthreads();
    }
    if (tid == 0)
        pred[b*LL + l] = (float)(0x7FFFFFFFu - (unsigned)(best & 0xFFFFFFFFu));
}

extern "C" void kernel_launch(void* const* d_in, const int* in_sizes, int n_in,
                              void* d_out, int out_size, void* d_ws, size_t ws_size,
                              hipStream_t stream) {
    (void)in_sizes; (void)n_in; (void)out_size; (void)ws_size;
    const float* sent = (const float*)d_in[0];
    const float* hid  = (const float*)d_in[1];
    const float* Wih  = (const float*)d_in[2];
    const float* Whh  = (const float*)d_in[3];
    const float* bih  = (const float*)d_in[4];
    const float* bhh  = (const float*)d_in[5];
    const float* Wp   = (const float*)d_in[6];
    const float* bp   = (const float*)d_in[7];
    const float* Wv   = (const float*)d_in[8];
    const float* bv   = (const float*)d_in[9];
    float* out = (float*)d_out;

    float* ws  = (float*)d_ws;
    float* hst = ws + OFF_H;                       // [33][64][1024]
    float* hT  = ws + OFF_HT;                      // [2][256][64][4]
    unsigned* rowmax = (unsigned*)(ws + OFF_RM);   // [2048]
    float* gx  = ws + OFF_GX;                      // [32][64][4096]
    // Apack aliases the gx region (gx is dead once the recurrence finishes)
    unsigned short* Ahi = (unsigned short*)(ws + OFF_GX);
    unsigned short* Alo = Ahi + (size_t)2048*HH;

    init_kernel<<<dim3(BB, 8), 128, 0, stream>>>(hid, Wp, bp, hst, hT, rowmax);
    gates_x_kernel<<<dim3(LL, GG/64), 256, 0, stream>>>(sent, Wih, bih, bhh, gx);

    {
        const float* gxp = gx;
        const float* Whhp = Whh;
        float* hstp = hst;
        float* hTp = hT;
        void* kargs[] = { (void*)&gxp, (void*)&Whhp, (void*)&hstp, (void*)&hTp };
        hipLaunchCooperativeKernel((void*)lstm_persist_kernel, dim3(256), dim3(256),
                                   kargs, (16*1024 + 16*64)*sizeof(float), stream);
    }

    hsplit_kernel<<<dim3(1024), 256, 0, stream>>>(hst + (size_t)BB*HH, Ahi, Alo);
    logits_mfma_kernel<<<dim3(16, VV/128), 256, 0, stream>>>(Ahi, Alo, Wv, bv, out, rowmax);
    argmax_kernel<<<dim3(LL*BB), 256, 0, stream>>>(
        out, rowmax, hst + (size_t)BB*HH, Wv, bv, out + (size_t)BB*LL*VV);
}

// Round 2
// 2817.709 us; speedup vs baseline: 1.3011x; 1.0688x over previous
//
#include <hip/hip_runtime.h>
#include <hip/hip_cooperative_groups.h>

namespace cg = cooperative_groups;

#define BB 64
#define LL 32
#define DD 512
#define HH 1024
#define GG 4096   // 4*H
#define VV 32000
#define EHH 512
#define ELL 40

// ws layout (float units)
#define OFF_H   0                          // hstates: [33][64][1024] (row 0 = h0)
#define OFF_HT  (33*BB*HH)                 // hT: [2][1024][64]  (h k-major, parity dbuf)
#define OFF_RM  (OFF_HT + 2*HH*BB)         // rowmax: 2048 u32 keys
#define OFF_GX  (OFF_RM + 2048)            // gxT: [32][4096][64]; later aliased by Apack

typedef __attribute__((ext_vector_type(8))) short bf16x8;
typedef __attribute__((ext_vector_type(4))) float f32x4;

__device__ __forceinline__ unsigned long long packkey(float v, int n) {
    unsigned u = __float_as_uint(v);
    u = (u & 0x80000000u) ? ~u : (u | 0x80000000u);
    return ((unsigned long long)u << 32) | (unsigned)(0x7FFFFFFF - n);
}
__device__ __forceinline__ unsigned key32(float v) {
    unsigned u = __float_as_uint(v);
    return (u & 0x80000000u) ? ~u : (u | 0x80000000u);
}
__device__ __forceinline__ float keyinv(unsigned k) {
    unsigned u = (k & 0x80000000u) ? (k & 0x7FFFFFFFu) : ~k;
    return __uint_as_float(u);
}
__device__ __forceinline__ unsigned short f2bf(float v) {
    unsigned u = __float_as_uint(v);
    return (unsigned short)((u + 0x7FFFu + ((u >> 16) & 1u)) >> 16);
}
__device__ __forceinline__ float bf2f(unsigned short b) {
    return __uint_as_float(((unsigned)b) << 16);
}

// ---- hx0 = hidden_state[:, -1, :] @ W_p.T + b_p ; seed hT[0] (k-major); zero rowmax ----
__global__ __launch_bounds__(128) void init_kernel(
    const float* __restrict__ hid, const float* __restrict__ Wp,
    const float* __restrict__ bp, float* __restrict__ hst,
    float* __restrict__ hT, unsigned* __restrict__ rowmax)
{
    int b = blockIdx.x;
    int h = blockIdx.y * 128 + threadIdx.x;
    const float4* hrow = (const float4*)(hid + ((size_t)b*ELL + (ELL-1))*EHH);
    const float4* wrow = (const float4*)(Wp + (size_t)h*EHH);
    float acc = 0.f;
    #pragma unroll 4
    for (int k = 0; k < EHH/4; ++k) {
        float4 a = hrow[k], w = wrow[k];
        acc += a.x*w.x + a.y*w.y + a.z*w.z + a.w*w.w;
    }
    float v = acc + bp[h];
    hst[(size_t)b*HH + h] = v;
    hT[(size_t)h*BB + b] = v;               // parity-0 buffer, [k][b]
    int tg = (b*8 + blockIdx.y)*128 + threadIdx.x;
    if (tg < LL*BB) rowmax[tg] = 0u;
}

// ---- Whh transpose: WT[k][4096] = Whh[row][k]  (WT lives in d_out scratch) ----
__global__ __launch_bounds__(256) void whhT_kernel(
    const float* __restrict__ W, float* __restrict__ WT)
{
    __shared__ float t[64][65];
    const int bx = blockIdx.x;    // row tile (4096/64)
    const int by = blockIdx.y;    // k tile (1024/64)
    const int tid = threadIdx.x;
    const int c4 = (tid & 15) * 4, rr = tid >> 4;
    #pragma unroll
    for (int p = 0; p < 4; ++p) {
        int r = p*16 + rr;
        float4 v = *(const float4*)(W + ((size_t)(bx*64 + r))*HH + by*64 + c4);
        t[r][c4+0] = v.x; t[r][c4+1] = v.y; t[r][c4+2] = v.z; t[r][c4+3] = v.w;
    }
    __syncthreads();
    #pragma unroll
    for (int p = 0; p < 4; ++p) {
        int k = p*16 + rr;
        float4 o;
        o.x = t[c4+0][k]; o.y = t[c4+1][k]; o.z = t[c4+2][k]; o.w = t[c4+3][k];
        *(float4*)(WT + ((size_t)(by*64 + k))*GG + bx*64 + c4) = o;
    }
}

// ---- gates_x, TRANSPOSED output: gxT[l][gate][b] ----
#define KT 16
__global__ __launch_bounds__(256) void gates_x_kernel(
    const float* __restrict__ x, const float* __restrict__ Wih,
    const float* __restrict__ bih, const float* __restrict__ bhh,
    float* __restrict__ gxT)
{
    __shared__ float As[KT][68];   // Wih tile (gates)
    __shared__ float Bs[KT][68];   // x tile (batches)
    const int l  = blockIdx.x;
    const int n0 = blockIdx.y * 64;          // gate tile base
    const int tid = threadIdx.x;
    const int tx = tid & 15, ty = tid >> 4;
    float acc[4][4] = {};
    for (int k0 = 0; k0 < DD; k0 += KT) {
        int i = tid * 4;
        int m = i >> 4, kk = i & 15;
        float4 a = *(const float4*)(Wih + (size_t)(n0+m)*DD + k0 + kk);
        As[kk+0][m]=a.x; As[kk+1][m]=a.y; As[kk+2][m]=a.z; As[kk+3][m]=a.w;
        float4 w = *(const float4*)(x + ((size_t)m*LL + l)*DD + k0 + kk);
        Bs[kk+0][m]=w.x; Bs[kk+1][m]=w.y; Bs[kk+2][m]=w.z; Bs[kk+3][m]=w.w;
        __syncthreads();
        #pragma unroll
        for (int k = 0; k < KT; ++k) {
            float4 av = *(const float4*)&As[k][ty*4];
            float4 bv = *(const float4*)&Bs[k][tx*4];
            float aa[4] = {av.x,av.y,av.z,av.w};
            float bb2[4] = {bv.x,bv.y,bv.z,bv.w};
            #pragma unroll
            for (int i2 = 0; i2 < 4; ++i2)
                #pragma unroll
                for (int j = 0; j < 4; ++j)
                    acc[i2][j] += aa[i2]*bb2[j];
        }
        __syncthreads();
    }
    #pragma unroll
    for (int i2 = 0; i2 < 4; ++i2) {
        int g = n0 + ty*4 + i2;              // global gate row
        float bias = bih[g] + bhh[g];
        float4 o;
        o.x = acc[i2][0] + bias;
        o.y = acc[i2][1] + bias;
        o.z = acc[i2][2] + bias;
        o.w = acc[i2][3] + bias;
        *(float4*)(gxT + ((size_t)l*GG + g)*BB + tx*4) = o;
    }
}

// ---- persistent LSTM v3: 256 wgs x 1024 thr (16 waves), W/h direct from L2 ----
// wave = k-slice of 64; lane: gate gq=lane>>4 (rows gq*4+j), batches b0=(lane&15)*4.
// acc[j][b] outer product: per k = 1 b128 (WT) + 1 b128 (hT) + 16 FMA.
__global__ __launch_bounds__(1024) void lstm_persist_kernel(
    const float* __restrict__ gxT,   // [32][4096][64]
    const float* __restrict__ WT,    // [1024][4096] (k-major, in d_out scratch)
    float* __restrict__ hst,         // [33][64][1024]
    float* __restrict__ hT)          // [2][1024][64]
{
    extern __shared__ float Gs[];    // [16 rows][16 kh][64 b] = 64 KB
    const int w = blockIdx.x;
    const int h0 = w*4;
    const int tid = threadIdx.x;
    const int wid = tid >> 6;        // kh 0..15
    const int lane = tid & 63;
    const int gq = lane >> 4;        // gate for this lane's rows
    const int b0 = (lane & 15) * 4;

    float c = 0.f;
    cg::grid_group grid = cg::this_grid();

    for (int s = 1; s <= LL; ++s) {
        const float* hprev = hT + (((s-1)&1) ? (HH*BB) : 0);
        // prefetch gate-bias (pre-accumulated x-gates) for update threads
        float gxv0=0.f, gxv1=0.f, gxv2=0.f, gxv3=0.f;
        if (wid < 4) {
            const float* gp = gxT + ((size_t)(s-1)*GG + h0 + wid)*BB + lane;
            gxv0 = gp[0*HH*BB];
            gxv1 = gp[1*HH*BB];
            gxv2 = gp[2*HH*BB];
            gxv3 = gp[3*HH*BB];
        }
        // ---- partial dot over k in [wid*64, wid*64+64) ----
        f32x4 a0 = {0,0,0,0}, a1 = {0,0,0,0}, a2 = {0,0,0,0}, a3 = {0,0,0,0};
        {
            const float* hp = hprev + (size_t)(wid*64)*BB + b0;
            const float* wp = WT + (size_t)(wid*64)*GG + gq*HH + h0;
            #pragma unroll 8
            for (int k = 0; k < 64; ++k) {
                float4 hv = *(const float4*)(hp + (size_t)k*BB);
                float4 wv = *(const float4*)(wp + (size_t)k*GG);
                a0.x += wv.x*hv.x; a0.y += wv.x*hv.y; a0.z += wv.x*hv.z; a0.w += wv.x*hv.w;
                a1.x += wv.y*hv.x; a1.y += wv.y*hv.y; a1.z += wv.y*hv.z; a1.w += wv.y*hv.w;
                a2.x += wv.z*hv.x; a2.y += wv.z*hv.y; a2.z += wv.z*hv.z; a2.w += wv.z*hv.w;
                a3.x += wv.w*hv.x; a3.y += wv.w*hv.y; a3.z += wv.w*hv.z; a3.w += wv.w*hv.w;
            }
        }
        // write partials: Gs[(gq*4+j)*16 + wid][b0..b0+3]
        *(f32x4*)&Gs[(((gq*4+0)*16) + wid)*64 + b0] = a0;
        *(f32x4*)&Gs[(((gq*4+1)*16) + wid)*64 + b0] = a1;
        *(f32x4*)&Gs[(((gq*4+2)*16) + wid)*64 + b0] = a2;
        *(f32x4*)&Gs[(((gq*4+3)*16) + wid)*64 + b0] = a3;
        __syncthreads();
        // ---- update: thread (wid=j<4, lane=b) owns h = h0+j ----
        if (wid < 4) {
            int j = wid, b = lane;
            float gacc[4] = {gxv0, gxv1, gxv2, gxv3};
            #pragma unroll
            for (int g = 0; g < 4; ++g) {
                const float* q = Gs + (size_t)((g*4 + j)*16)*64 + b;
                float sum = 0.f;
                #pragma unroll
                for (int kh = 0; kh < 16; ++kh) sum += q[kh*64];
                gacc[g] += sum;
            }
            float si = 1.f/(1.f + expf(-gacc[0]));
            float sf = 1.f/(1.f + expf(-gacc[1]));
            float so = 1.f/(1.f + expf(-gacc[3]));
            float cn = sf*c + si*tanhf(gacc[2]);
            float hn = so*tanhf(cn);
            c = cn;
            int h = h0 + j;
            hst[((size_t)s*BB + b)*HH + h] = hn;
            float* hTn = hT + ((s&1) ? (HH*BB) : 0);
            hTn[(size_t)h*BB + b] = hn;
        }
        grid.sync();
    }
}

// ---- split hs rows (2048x1024 f32) into MFMA-fragment-linear bf16 hi/lo ----
__global__ __launch_bounds__(256) void hsplit_kernel(
    const float* __restrict__ hs, unsigned short* __restrict__ Ahi,
    unsigned short* __restrict__ Alo)
{
    int t = blockIdx.x*256 + threadIdx.x;       // 2048 rows x 128 k-octets
    int row = t >> 7, ko = (t & 127) << 3;
    const float* src = hs + (size_t)row*HH + ko;
    float4 f0 = *(const float4*)(src);
    float4 f1 = *(const float4*)(src + 4);
    float vs[8] = {f0.x,f0.y,f0.z,f0.w,f1.x,f1.y,f1.z,f1.w};
    union { bf16x8 v; unsigned short u[8]; } hi, lo;
    #pragma unroll
    for (int e = 0; e < 8; ++e) {
        unsigned short h = f2bf(vs[e]);
        hi.u[e] = h;
        lo.u[e] = f2bf(vs[e] - bf2f(h));
    }
    size_t off = ((((size_t)(row>>4)*32 + (ko>>5))*64) + ((ko&31)>>3)*16 + (row&15))*8;
    *(bf16x8*)(Ahi + off) = hi.v;
    *(bf16x8*)(Alo + off) = lo.v;
}

// ---- logits = hs @ W_v.T + b_v via bf16x3 split MFMA; approx per-row max tracked ----
__global__ __launch_bounds__(256, 2) void logits_mfma_kernel(
    const unsigned short* __restrict__ Ahi, const unsigned short* __restrict__ Alo,
    const float* __restrict__ Wv, const float* __restrict__ bv,
    float* __restrict__ out, unsigned* __restrict__ rowmax)
{
    __shared__ bf16x8 Bhi[4][128];
    __shared__ bf16x8 Blo[4][128];
    const int rb = blockIdx.x;        // row block 0..15   (128 rows)
    const int cb = blockIdx.y;        // col block 0..249  (128 cols)
    const int n0 = cb*128;
    const int tid = threadIdx.x;
    const int wid = tid >> 6, lane = tid & 63;
    const int wy = wid >> 1, wx = wid & 1;      // 2x2 waves, 64x64 each
    const int l15 = lane & 15, l4 = lane >> 4;
    f32x4 acc[4][4] = {};

    const int sc = tid >> 1, skh = tid & 1;     // staging: col 0..127, k-half 0..1
    const float* wsrc = Wv + (size_t)(n0 + sc)*HH + skh*16;
    const size_t abase = (size_t)(rb*8 + wy*4)*32;

    for (int ks = 0; ks < 32; ++ks) {
        float4 f0 = *(const float4*)(wsrc + ks*32);
        float4 f1 = *(const float4*)(wsrc + ks*32 + 4);
        float4 f2 = *(const float4*)(wsrc + ks*32 + 8);
        float4 f3 = *(const float4*)(wsrc + ks*32 + 12);
        __syncthreads();
        {
            float va[8] = {f0.x,f0.y,f0.z,f0.w,f1.x,f1.y,f1.z,f1.w};
            float vb[8] = {f2.x,f2.y,f2.z,f2.w,f3.x,f3.y,f3.z,f3.w};
            union { bf16x8 v; unsigned short u[8]; } h0, l0, h1, l1;
            #pragma unroll
            for (int e = 0; e < 8; ++e) {
                unsigned short ha = f2bf(va[e]);
                h0.u[e] = ha; l0.u[e] = f2bf(va[e] - bf2f(ha));
                unsigned short hb = f2bf(vb[e]);
                h1.u[e] = hb; l1.u[e] = f2bf(vb[e] - bf2f(hb));
            }
            Bhi[skh*2+0][sc] = h0.v;  Blo[skh*2+0][sc] = l0.v;
            Bhi[skh*2+1][sc] = h1.v;  Blo[skh*2+1][sc] = l1.v;
        }
        __syncthreads();
        bf16x8 ah[4], al[4], bh[4], bl[4];
        #pragma unroll
        for (int mf = 0; mf < 4; ++mf) {
            size_t o = ((abase + (size_t)mf*32 + ks)*64 + lane)*8;
            ah[mf] = *(const bf16x8*)(Ahi + o);
            al[mf] = *(const bf16x8*)(Alo + o);
        }
        #pragma unroll
        for (int nf = 0; nf < 4; ++nf) {
            int cc = wx*64 + nf*16 + l15;
            bh[nf] = Bhi[l4][cc];
            bl[nf] = Blo[l4][cc];
        }
        #pragma unroll
        for (int mf = 0; mf < 4; ++mf)
            #pragma unroll
            for (int nf = 0; nf < 4; ++nf) {
                acc[mf][nf] = __builtin_amdgcn_mfma_f32_16x16x32_bf16(ah[mf], bh[nf], acc[mf][nf], 0,0,0);
                acc[mf][nf] = __builtin_amdgcn_mfma_f32_16x16x32_bf16(ah[mf], bl[nf], acc[mf][nf], 0,0,0);
                acc[mf][nf] = __builtin_amdgcn_mfma_f32_16x16x32_bf16(al[mf], bh[nf], acc[mf][nf], 0,0,0);
            }
    }
    unsigned rk[4][4];
    #pragma unroll
    for (int mf = 0; mf < 4; ++mf)
        #pragma unroll
        for (int j = 0; j < 4; ++j) rk[mf][j] = 0u;
    #pragma unroll
    for (int mf = 0; mf < 4; ++mf) {
        int rowg = rb*128 + wy*64 + mf*16 + l4*4;
        #pragma unroll
        for (int nf = 0; nf < 4; ++nf) {
            int col = n0 + wx*64 + nf*16 + l15;
            float bvv = bv[col];
            #pragma unroll
            for (int j = 0; j < 4; ++j) {
                float v = acc[mf][nf][j] + bvv;
                int row = rowg + j;
                int b = row & 63, l = row >> 6;
                out[((size_t)b*LL + l)*VV + col] = v;
                unsigned key = key32(v);
                if (key > rk[mf][j]) rk[mf][j] = key;
            }
        }
    }
    #pragma unroll
    for (int o = 1; o < 16; o <<= 1)
        #pragma unroll
        for (int mf = 0; mf < 4; ++mf)
            #pragma unroll
            for (int j = 0; j < 4; ++j) {
                unsigned t = __shfl_xor(rk[mf][j], o);
                if (t > rk[mf][j]) rk[mf][j] = t;
            }
    if (l15 == 0) {
        #pragma unroll
        for (int mf = 0; mf < 4; ++mf)
            #pragma unroll
            for (int j = 0; j < 4; ++j)
                atomicMax(&rowmax[rb*128 + wy*64 + mf*16 + l4*4 + j], rk[mf][j]);
    }
}

// ---- exact-rescued argmax ----
__global__ __launch_bounds__(256) void argmax_kernel(
    const float* __restrict__ out, const unsigned* __restrict__ rowmax,
    const float* __restrict__ hs, const float* __restrict__ Wv,
    const float* __restrict__ bv, float* __restrict__ pred)
{
    const int r = blockIdx.x;            // r = l*64 + b
    const int b = r & 63, l = r >> 6;
    const int tid = threadIdx.x;
    const float* row = out + ((size_t)b*LL + l)*VV;
    const float thr = keyinv(rowmax[r]) - 2e-3f;
    __shared__ int cnt;
    __shared__ int cand[32];
    __shared__ float ps[4];
    if (tid == 0) cnt = 0;
    __syncthreads();
    for (int i = tid*4; i < VV; i += 1024) {
        float4 v = *(const float4*)(row + i);
        if (v.x >= thr) { int p = atomicAdd(&cnt,1); if (p < 32) cand[p] = i; }
        if (v.y >= thr) { int p = atomicAdd(&cnt,1); if (p < 32) cand[p] = i+1; }
        if (v.z >= thr) { int p = atomicAdd(&cnt,1); if (p < 32) cand[p] = i+2; }
        if (v.w >= thr) { int p = atomicAdd(&cnt,1); if (p < 32) cand[p] = i+3; }
    }
    __syncthreads();
    int nc = cnt < 32 ? cnt : 32;
    unsigned long long best = 0ULL;
    const float* hrow = hs + (size_t)r*HH;
    float4 a = *(const float4*)(hrow + tid*4);
    for (int ci = 0; ci < nc; ++ci) {
        int n = cand[ci];
        float4 wv = *(const float4*)(Wv + (size_t)n*HH + tid*4);
        float p = a.x*wv.x + a.y*wv.y + a.z*wv.z + a.w*wv.w;
        #pragma unroll
        for (int o = 1; o < 64; o <<= 1) p += __shfl_xor(p, o);
        if ((tid & 63) == 0) ps[tid >> 6] = p;
        __syncthreads();
        if (tid == 0) {
            float tot = ps[0] + ps[1] + ps[2] + ps[3] + bv[n];
            unsigned long long k2 = packkey(tot, n);
            if (k2 > best) best = k2;
        }
        __syncthreads();
    }
    if (tid == 0)
        pred[b*LL + l] = (float)(0x7FFFFFFFu - (unsigned)(best & 0xFFFFFFFFu));
}

extern "C" void kernel_launch(void* const* d_in, const int* in_sizes, int n_in,
                              void* d_out, int out_size, void* d_ws, size_t ws_size,
                              hipStream_t stream) {
    (void)in_sizes; (void)n_in; (void)out_size; (void)ws_size;
    const float* sent = (const float*)d_in[0];
    const float* hid  = (const float*)d_in[1];
    const float* Wih  = (const float*)d_in[2];
    const float* Whh  = (const float*)d_in[3];
    const float* bih  = (const float*)d_in[4];
    const float* bhh  = (const float*)d_in[5];
    const float* Wp   = (const float*)d_in[6];
    const float* bp   = (const float*)d_in[7];
    const float* Wv   = (const float*)d_in[8];
    const float* bv   = (const float*)d_in[9];
    float* out = (float*)d_out;

    float* ws  = (float*)d_ws;
    float* hst = ws + OFF_H;                       // [33][64][1024]
    float* hT  = ws + OFF_HT;                      // [2][1024][64]
    unsigned* rowmax = (unsigned*)(ws + OFF_RM);   // [2048]
    float* gxT = ws + OFF_GX;                      // [32][4096][64]
    unsigned short* Ahi = (unsigned short*)(ws + OFF_GX);   // alias (gxT dead post-lstm)
    unsigned short* Alo = Ahi + (size_t)2048*HH;

    // WT scratch lives in d_out (dead until logits_mfma writes it much later)
    float* WT = out;                               // [1024][4096] = 16.8 MB << out_size

    init_kernel<<<dim3(BB, 8), 128, 0, stream>>>(hid, Wp, bp, hst, hT, rowmax);
    whhT_kernel<<<dim3(GG/64, HH/64), 256, 0, stream>>>(Whh, WT);
    gates_x_kernel<<<dim3(LL, GG/64), 256, 0, stream>>>(sent, Wih, bih, bhh, gxT);

    {
        const float* gxp = gxT;
        const float* WTp = WT;
        float* hstp = hst;
        float* hTp = hT;
        void* kargs[] = { (void*)&gxp, (void*)&WTp, (void*)&hstp, (void*)&hTp };
        hipLaunchCooperativeKernel((void*)lstm_persist_kernel, dim3(256), dim3(1024),
                                   kargs, 16*16*64*sizeof(float), stream);
    }

    hsplit_kernel<<<dim3(1024), 256, 0, stream>>>(hst + (size_t)BB*HH, Ahi, Alo);
    logits_mfma_kernel<<<dim3(16, VV/128), 256, 0, stream>>>(Ahi, Alo, Wv, bv, out, rowmax);
    argmax_kernel<<<dim3(LL*BB), 256, 0, stream>>>(
        out, rowmax, hst + (size_t)BB*HH, Wv, bv, out + (size_t)BB*LL*VV);
}

// Round 3
// 2404.489 us; speedup vs baseline: 1.5247x; 1.1719x over previous
//
#include <hip/hip_runtime.h>
#include <hip/hip_cooperative_groups.h>

namespace cg = cooperative_groups;

#define BB 64
#define LL 32
#define DD 512
#define HH 1024
#define GG 4096   // 4*H
#define VV 32000
#define EHH 512
#define ELL 40

// ws layout (float units)
#define OFF_H   0                          // hstates: [33][64][1024] (row 0 = h0)
#define OFF_HT  (33*BB*HH)                 // hT: [2][1024][64]  (h k-major, parity dbuf)
#define OFF_RM  (OFF_HT + 2*HH*BB)         // rowmax: 2048 u32 keys
#define OFF_GX  (OFF_RM + 2048)            // gxT: [32][4096][64]; later aliased by Apack

typedef __attribute__((ext_vector_type(8))) short bf16x8;
typedef __attribute__((ext_vector_type(4))) float f32x4;

__device__ __forceinline__ unsigned long long packkey(float v, int n) {
    unsigned u = __float_as_uint(v);
    u = (u & 0x80000000u) ? ~u : (u | 0x80000000u);
    return ((unsigned long long)u << 32) | (unsigned)(0x7FFFFFFF - n);
}
__device__ __forceinline__ unsigned key32(float v) {
    unsigned u = __float_as_uint(v);
    return (u & 0x80000000u) ? ~u : (u | 0x80000000u);
}
__device__ __forceinline__ float keyinv(unsigned k) {
    unsigned u = (k & 0x80000000u) ? (k & 0x7FFFFFFFu) : ~k;
    return __uint_as_float(u);
}
__device__ __forceinline__ unsigned short f2bf(float v) {
    unsigned u = __float_as_uint(v);
    return (unsigned short)((u + 0x7FFFu + ((u >> 16) & 1u)) >> 16);
}
__device__ __forceinline__ float bf2f(unsigned short b) {
    return __uint_as_float(((unsigned)b) << 16);
}

// ---- hx0 = hidden_state[:, -1, :] @ W_p.T + b_p ; seed hT[0] (k-major); zero rowmax ----
__global__ __launch_bounds__(128) void init_kernel(
    const float* __restrict__ hid, const float* __restrict__ Wp,
    const float* __restrict__ bp, float* __restrict__ hst,
    float* __restrict__ hT, unsigned* __restrict__ rowmax)
{
    int b = blockIdx.x;
    int h = blockIdx.y * 128 + threadIdx.x;
    const float4* hrow = (const float4*)(hid + ((size_t)b*ELL + (ELL-1))*EHH);
    const float4* wrow = (const float4*)(Wp + (size_t)h*EHH);
    float acc = 0.f;
    #pragma unroll 4
    for (int k = 0; k < EHH/4; ++k) {
        float4 a = hrow[k], w = wrow[k];
        acc += a.x*w.x + a.y*w.y + a.z*w.z + a.w*w.w;
    }
    float v = acc + bp[h];
    hst[(size_t)b*HH + h] = v;
    hT[(size_t)h*BB + b] = v;               // parity-0 buffer, [k][b]
    int tg = (b*8 + blockIdx.y)*128 + threadIdx.x;
    if (tg < LL*BB) rowmax[tg] = 0u;
}

// ---- gates_x, TRANSPOSED output: gxT[l][gate][b] ----
#define KT 16
__global__ __launch_bounds__(256) void gates_x_kernel(
    const float* __restrict__ x, const float* __restrict__ Wih,
    const float* __restrict__ bih, const float* __restrict__ bhh,
    float* __restrict__ gxT)
{
    __shared__ float As[KT][68];   // Wih tile (gates)
    __shared__ float Bs[KT][68];   // x tile (batches)
    const int l  = blockIdx.x;
    const int n0 = blockIdx.y * 64;          // gate tile base
    const int tid = threadIdx.x;
    const int tx = tid & 15, ty = tid >> 4;
    float acc[4][4] = {};
    for (int k0 = 0; k0 < DD; k0 += KT) {
        int i = tid * 4;
        int m = i >> 4, kk = i & 15;
        float4 a = *(const float4*)(Wih + (size_t)(n0+m)*DD + k0 + kk);
        As[kk+0][m]=a.x; As[kk+1][m]=a.y; As[kk+2][m]=a.z; As[kk+3][m]=a.w;
        float4 w = *(const float4*)(x + ((size_t)m*LL + l)*DD + k0 + kk);
        Bs[kk+0][m]=w.x; Bs[kk+1][m]=w.y; Bs[kk+2][m]=w.z; Bs[kk+3][m]=w.w;
        __syncthreads();
        #pragma unroll
        for (int k = 0; k < KT; ++k) {
            float4 av = *(const float4*)&As[k][ty*4];
            float4 bv = *(const float4*)&Bs[k][tx*4];
            float aa[4] = {av.x,av.y,av.z,av.w};
            float bb2[4] = {bv.x,bv.y,bv.z,bv.w};
            #pragma unroll
            for (int i2 = 0; i2 < 4; ++i2)
                #pragma unroll
                for (int j = 0; j < 4; ++j)
                    acc[i2][j] += aa[i2]*bb2[j];
        }
        __syncthreads();
    }
    #pragma unroll
    for (int i2 = 0; i2 < 4; ++i2) {
        int g = n0 + ty*4 + i2;              // global gate row
        float bias = bih[g] + bhh[g];
        float4 o;
        o.x = acc[i2][0] + bias;
        o.y = acc[i2][1] + bias;
        o.z = acc[i2][2] + bias;
        o.w = acc[i2][3] + bias;
        *(float4*)(gxT + ((size_t)l*GG + g)*BB + tx*4) = o;
    }
}

// ---- persistent LSTM v4: 256 wgs x 1024 thr; wg's 16 W_hh rows resident in LDS ----
// wave = k-slice of 64; lane: gate gq=lane>>4 (rows gq*4+j), batches b0=(lane&15)*4.
// Per k: 1 ds_read_b128 (W, 16-lane broadcast) + 1 global b128 (h) + 16 FMA.
__global__ __launch_bounds__(1024) void lstm_persist_kernel(
    const float* __restrict__ gxT,   // [32][4096][64]
    const float* __restrict__ Whh,   // [4096][1024] original layout
    float* __restrict__ hst,         // [33][64][1024]
    float* __restrict__ hT)          // [2][1024][64]
{
    extern __shared__ float smem[];
    float* Ws = smem;                // [1024 k][16 c] = 64 KB, c = gate*4 + j
    float* Gs = smem + 16384;        // [16 rows][16 kh][64 b] = 64 KB
    const int w = blockIdx.x;
    const int h0 = w*4;
    const int tid = threadIdx.x;
    const int wid = tid >> 6;        // kh 0..15
    const int lane = tid & 63;
    const int gq = lane >> 4;        // gate for this lane's rows
    const int b0 = (lane & 15) * 4;

    // one-time W_hh slice load: rows g*HH + h0 + j (coalesced), k-major into LDS
    {
        int rr = tid >> 6;           // 0..15 -> (g, j)
        int g = rr >> 2, j = rr & 3;
        const float* src = Whh + ((size_t)(g*HH + h0 + j))*HH;
        int kbase = (tid & 63) * 4;
        #pragma unroll
        for (int cch = 0; cch < 4; ++cch) {
            float4 v = *(const float4*)(src + kbase + cch*256);
            Ws[(kbase + cch*256 + 0)*16 + rr] = v.x;
            Ws[(kbase + cch*256 + 1)*16 + rr] = v.y;
            Ws[(kbase + cch*256 + 2)*16 + rr] = v.z;
            Ws[(kbase + cch*256 + 3)*16 + rr] = v.w;
        }
    }
    float c = 0.f;
    cg::grid_group grid = cg::this_grid();
    __syncthreads();

    for (int s = 1; s <= LL; ++s) {
        const float* hprev = hT + (((s-1)&1) ? (HH*BB) : 0);
        // prefetch gate-bias (pre-accumulated x-gates) for update threads
        float gxv0=0.f, gxv1=0.f, gxv2=0.f, gxv3=0.f;
        if (wid < 4) {
            const float* gp = gxT + ((size_t)(s-1)*GG + h0 + wid)*BB + lane;
            gxv0 = gp[0*HH*BB];
            gxv1 = gp[1*HH*BB];
            gxv2 = gp[2*HH*BB];
            gxv3 = gp[3*HH*BB];
        }
        // ---- partial dot over k in [wid*64, wid*64+64) ----
        f32x4 a0 = {0,0,0,0}, a1 = {0,0,0,0}, a2 = {0,0,0,0}, a3 = {0,0,0,0};
        {
            const float* hp = hprev + (size_t)(wid*64)*BB + b0;
            const float* wp = Ws + (wid*64)*16 + gq*4;
            #pragma unroll 8
            for (int k = 0; k < 64; ++k) {
                float4 hv = *(const float4*)(hp + (size_t)k*BB);
                float4 wv = *(const float4*)(wp + k*16);
                a0.x += wv.x*hv.x; a0.y += wv.x*hv.y; a0.z += wv.x*hv.z; a0.w += wv.x*hv.w;
                a1.x += wv.y*hv.x; a1.y += wv.y*hv.y; a1.z += wv.y*hv.z; a1.w += wv.y*hv.w;
                a2.x += wv.z*hv.x; a2.y += wv.z*hv.y; a2.z += wv.z*hv.z; a2.w += wv.z*hv.w;
                a3.x += wv.w*hv.x; a3.y += wv.w*hv.y; a3.z += wv.w*hv.z; a3.w += wv.w*hv.w;
            }
        }
        // write partials: Gs[(gq*4+j)*16 + wid][b0..b0+3]
        *(f32x4*)&Gs[(((gq*4+0)*16) + wid)*64 + b0] = a0;
        *(f32x4*)&Gs[(((gq*4+1)*16) + wid)*64 + b0] = a1;
        *(f32x4*)&Gs[(((gq*4+2)*16) + wid)*64 + b0] = a2;
        *(f32x4*)&Gs[(((gq*4+3)*16) + wid)*64 + b0] = a3;
        __syncthreads();
        // ---- update: thread (wid=j<4, lane=b) owns h = h0+j ----
        if (wid < 4) {
            int j = wid, b = lane;
            float gacc[4] = {gxv0, gxv1, gxv2, gxv3};
            #pragma unroll
            for (int g = 0; g < 4; ++g) {
                const float* q = Gs + (size_t)((g*4 + j)*16)*64 + b;
                float sum = 0.f;
                #pragma unroll
                for (int kh = 0; kh < 16; ++kh) sum += q[kh*64];
                gacc[g] += sum;
            }
            float si = 1.f/(1.f + expf(-gacc[0]));
            float sf = 1.f/(1.f + expf(-gacc[1]));
            float so = 1.f/(1.f + expf(-gacc[3]));
            float cn = sf*c + si*tanhf(gacc[2]);
            float hn = so*tanhf(cn);
            c = cn;
            int h = h0 + j;
            hst[((size_t)s*BB + b)*HH + h] = hn;
            float* hTn = hT + ((s&1) ? (HH*BB) : 0);
            hTn[(size_t)h*BB + b] = hn;
        }
        grid.sync();
    }
}

// ---- split hs rows (2048x1024 f32) into MFMA-fragment-linear bf16 hi/lo ----
__global__ __launch_bounds__(256) void hsplit_kernel(
    const float* __restrict__ hs, unsigned short* __restrict__ Ahi,
    unsigned short* __restrict__ Alo)
{
    int t = blockIdx.x*256 + threadIdx.x;       // 2048 rows x 128 k-octets
    int row = t >> 7, ko = (t & 127) << 3;
    const float* src = hs + (size_t)row*HH + ko;
    float4 f0 = *(const float4*)(src);
    float4 f1 = *(const float4*)(src + 4);
    float vs[8] = {f0.x,f0.y,f0.z,f0.w,f1.x,f1.y,f1.z,f1.w};
    union { bf16x8 v; unsigned short u[8]; } hi, lo;
    #pragma unroll
    for (int e = 0; e < 8; ++e) {
        unsigned short h = f2bf(vs[e]);
        hi.u[e] = h;
        lo.u[e] = f2bf(vs[e] - bf2f(h));
    }
    size_t off = ((((size_t)(row>>4)*32 + (ko>>5))*64) + ((ko&31)>>3)*16 + (row&15))*8;
    *(bf16x8*)(Ahi + off) = hi.v;
    *(bf16x8*)(Alo + off) = lo.v;
}

// ---- logits = hs @ W_v.T + b_v via bf16x3 split MFMA; approx per-row max tracked ----
__global__ __launch_bounds__(256, 2) void logits_mfma_kernel(
    const unsigned short* __restrict__ Ahi, const unsigned short* __restrict__ Alo,
    const float* __restrict__ Wv, const float* __restrict__ bv,
    float* __restrict__ out, unsigned* __restrict__ rowmax)
{
    __shared__ bf16x8 Bhi[4][128];
    __shared__ bf16x8 Blo[4][128];
    const int rb = blockIdx.x;        // row block 0..15   (128 rows)
    const int cb = blockIdx.y;        // col block 0..249  (128 cols)
    const int n0 = cb*128;
    const int tid = threadIdx.x;
    const int wid = tid >> 6, lane = tid & 63;
    const int wy = wid >> 1, wx = wid & 1;      // 2x2 waves, 64x64 each
    const int l15 = lane & 15, l4 = lane >> 4;
    f32x4 acc[4][4] = {};

    const int sc = tid >> 1, skh = tid & 1;     // staging: col 0..127, k-half 0..1
    const float* wsrc = Wv + (size_t)(n0 + sc)*HH + skh*16;
    const size_t abase = (size_t)(rb*8 + wy*4)*32;

    for (int ks = 0; ks < 32; ++ks) {
        float4 f0 = *(const float4*)(wsrc + ks*32);
        float4 f1 = *(const float4*)(wsrc + ks*32 + 4);
        float4 f2 = *(const float4*)(wsrc + ks*32 + 8);
        float4 f3 = *(const float4*)(wsrc + ks*32 + 12);
        __syncthreads();
        {
            float va[8] = {f0.x,f0.y,f0.z,f0.w,f1.x,f1.y,f1.z,f1.w};
            float vb[8] = {f2.x,f2.y,f2.z,f2.w,f3.x,f3.y,f3.z,f3.w};
            union { bf16x8 v; unsigned short u[8]; } h0, l0, h1, l1;
            #pragma unroll
            for (int e = 0; e < 8; ++e) {
                unsigned short ha = f2bf(va[e]);
                h0.u[e] = ha; l0.u[e] = f2bf(va[e] - bf2f(ha));
                unsigned short hb = f2bf(vb[e]);
                h1.u[e] = hb; l1.u[e] = f2bf(vb[e] - bf2f(hb));
            }
            Bhi[skh*2+0][sc] = h0.v;  Blo[skh*2+0][sc] = l0.v;
            Bhi[skh*2+1][sc] = h1.v;  Blo[skh*2+1][sc] = l1.v;
        }
        __syncthreads();
        bf16x8 ah[4], al[4], bh[4], bl[4];
        #pragma unroll
        for (int mf = 0; mf < 4; ++mf) {
            size_t o = ((abase + (size_t)mf*32 + ks)*64 + lane)*8;
            ah[mf] = *(const bf16x8*)(Ahi + o);
            al[mf] = *(const bf16x8*)(Alo + o);
        }
        #pragma unroll
        for (int nf = 0; nf < 4; ++nf) {
            int cc = wx*64 + nf*16 + l15;
            bh[nf] = Bhi[l4][cc];
            bl[nf] = Blo[l4][cc];
        }
        #pragma unroll
        for (int mf = 0; mf < 4; ++mf)
            #pragma unroll
            for (int nf = 0; nf < 4; ++nf) {
                acc[mf][nf] = __builtin_amdgcn_mfma_f32_16x16x32_bf16(ah[mf], bh[nf], acc[mf][nf], 0,0,0);
                acc[mf][nf] = __builtin_amdgcn_mfma_f32_16x16x32_bf16(ah[mf], bl[nf], acc[mf][nf], 0,0,0);
                acc[mf][nf] = __builtin_amdgcn_mfma_f32_16x16x32_bf16(al[mf], bh[nf], acc[mf][nf], 0,0,0);
            }
    }
    unsigned rk[4][4];
    #pragma unroll
    for (int mf = 0; mf < 4; ++mf)
        #pragma unroll
        for (int j = 0; j < 4; ++j) rk[mf][j] = 0u;
    #pragma unroll
    for (int mf = 0; mf < 4; ++mf) {
        int rowg = rb*128 + wy*64 + mf*16 + l4*4;
        #pragma unroll
        for (int nf = 0; nf < 4; ++nf) {
            int col = n0 + wx*64 + nf*16 + l15;
            float bvv = bv[col];
            #pragma unroll
            for (int j = 0; j < 4; ++j) {
                float v = acc[mf][nf][j] + bvv;
                int row = rowg + j;
                int b = row & 63, l = row >> 6;
                out[((size_t)b*LL + l)*VV + col] = v;
                unsigned key = key32(v);
                if (key > rk[mf][j]) rk[mf][j] = key;
            }
        }
    }
    #pragma unroll
    for (int o = 1; o < 16; o <<= 1)
        #pragma unroll
        for (int mf = 0; mf < 4; ++mf)
            #pragma unroll
            for (int j = 0; j < 4; ++j) {
                unsigned t = __shfl_xor(rk[mf][j], o);
                if (t > rk[mf][j]) rk[mf][j] = t;
            }
    if (l15 == 0) {
        #pragma unroll
        for (int mf = 0; mf < 4; ++mf)
            #pragma unroll
            for (int j = 0; j < 4; ++j)
                atomicMax(&rowmax[rb*128 + wy*64 + mf*16 + l4*4 + j], rk[mf][j]);
    }
}

// ---- exact-rescued argmax ----
__global__ __launch_bounds__(256) void argmax_kernel(
    const float* __restrict__ out, const unsigned* __restrict__ rowmax,
    const float* __restrict__ hs, const float* __restrict__ Wv,
    const float* __restrict__ bv, float* __restrict__ pred)
{
    const int r = blockIdx.x;            // r = l*64 + b
    const int b = r & 63, l = r >> 6;
    const int tid = threadIdx.x;
    const float* row = out + ((size_t)b*LL + l)*VV;
    const float thr = keyinv(rowmax[r]) - 2e-3f;
    __shared__ int cnt;
    __shared__ int cand[32];
    __shared__ float ps[4];
    if (tid == 0) cnt = 0;
    __syncthreads();
    for (int i = tid*4; i < VV; i += 1024) {
        float4 v = *(const float4*)(row + i);
        if (v.x >= thr) { int p = atomicAdd(&cnt,1); if (p < 32) cand[p] = i; }
        if (v.y >= thr) { int p = atomicAdd(&cnt,1); if (p < 32) cand[p] = i+1; }
        if (v.z >= thr) { int p = atomicAdd(&cnt,1); if (p < 32) cand[p] = i+2; }
        if (v.w >= thr) { int p = atomicAdd(&cnt,1); if (p < 32) cand[p] = i+3; }
    }
    __syncthreads();
    int nc = cnt < 32 ? cnt : 32;
    unsigned long long best = 0ULL;
    const float* hrow = hs + (size_t)r*HH;
    float4 a = *(const float4*)(hrow + tid*4);
    for (int ci = 0; ci < nc; ++ci) {
        int n = cand[ci];
        float4 wv = *(const float4*)(Wv + (size_t)n*HH + tid*4);
        float p = a.x*wv.x + a.y*wv.y + a.z*wv.z + a.w*wv.w;
        #pragma unroll
        for (int o = 1; o < 64; o <<= 1) p += __shfl_xor(p, o);
        if ((tid & 63) == 0) ps[tid >> 6] = p;
        __syncthreads();
        if (tid == 0) {
            float tot = ps[0] + ps[1] + ps[2] + ps[3] + bv[n];
            unsigned long long k2 = packkey(tot, n);
            if (k2 > best) best = k2;
        }
        __syncthreads();
    }
    if (tid == 0)
        pred[b*LL + l] = (float)(0x7FFFFFFFu - (unsigned)(best & 0xFFFFFFFFu));
}

extern "C" void kernel_launch(void* const* d_in, const int* in_sizes, int n_in,
                              void* d_out, int out_size, void* d_ws, size_t ws_size,
                              hipStream_t stream) {
    (void)in_sizes; (void)n_in; (void)out_size; (void)ws_size;
    const float* sent = (const float*)d_in[0];
    const float* hid  = (const float*)d_in[1];
    const float* Wih  = (const float*)d_in[2];
    const float* Whh  = (const float*)d_in[3];
    const float* bih  = (const float*)d_in[4];
    const float* bhh  = (const float*)d_in[5];
    const float* Wp   = (const float*)d_in[6];
    const float* bp   = (const float*)d_in[7];
    const float* Wv   = (const float*)d_in[8];
    const float* bv   = (const float*)d_in[9];
    float* out = (float*)d_out;

    float* ws  = (float*)d_ws;
    float* hst = ws + OFF_H;                       // [33][64][1024]
    float* hT  = ws + OFF_HT;                      // [2][1024][64]
    unsigned* rowmax = (unsigned*)(ws + OFF_RM);   // [2048]
    float* gxT = ws + OFF_GX;                      // [32][4096][64]
    unsigned short* Ahi = (unsigned short*)(ws + OFF_GX);   // alias (gxT dead post-lstm)
    unsigned short* Alo = Ahi + (size_t)2048*HH;

    init_kernel<<<dim3(BB, 8), 128, 0, stream>>>(hid, Wp, bp, hst, hT, rowmax);
    gates_x_kernel<<<dim3(LL, GG/64), 256, 0, stream>>>(sent, Wih, bih, bhh, gxT);

    {
        const float* gxp = gxT;
        const float* Whhp = Whh;
        float* hstp = hst;
        float* hTp = hT;
        void* kargs[] = { (void*)&gxp, (void*)&Whhp, (void*)&hstp, (void*)&hTp };
        hipLaunchCooperativeKernel((void*)lstm_persist_kernel, dim3(256), dim3(1024),
                                   kargs, 2*16384*sizeof(float), stream);
    }

    hsplit_kernel<<<dim3(1024), 256, 0, stream>>>(hst + (size_t)BB*HH, Ahi, Alo);
    logits_mfma_kernel<<<dim3(16, VV/128), 256, 0, stream>>>(Ahi, Alo, Wv, bv, out, rowmax);
    argmax_kernel<<<dim3(LL*BB), 256, 0, stream>>>(
        out, rowmax, hst + (size_t)BB*HH, Wv, bv, out + (size_t)BB*LL*VV);
}